// Round 9
// baseline (148.388 us; speedup 1.0000x reference)
//
#include <hip/hip_runtime.h>

#define B_    8
#define CIN_  64
#define COUT_ 64
#define H_    256
#define W_    256
#define HW_   65536

typedef __attribute__((ext_vector_type(8)))  short short8;    // 8 bf16 = 4 VGPRs
typedef __attribute__((ext_vector_type(16))) float f32x16;

static __device__ __forceinline__ unsigned short f2bf(float f) {
    union { float f; unsigned u; } v; v.f = f;
    unsigned r = (v.u + 0x7FFFu + ((v.u >> 16) & 1u)) >> 16;  // RNE
    return (unsigned short)r;
}

// v_cvt_pk_bf16_f32: dst = {lo: bf16(a), hi: bf16(b)}, RNE — 1 instr vs ~11.
static __device__ __forceinline__ unsigned cvtpk(float a, float b) {
    unsigned r;
    asm("v_cvt_pk_bf16_f32 %0, %1, %2" : "=v"(r) : "v"(a), "v"(b));
    return r;
}

// async global->LDS, 16B per lane. LDS dest = wave-uniform base + lane*16.
static __device__ __forceinline__ void gload16(void* lds, const void* g) {
    __builtin_amdgcn_global_load_lds(
        (const __attribute__((address_space(1))) unsigned int*)g,
        (__attribute__((address_space(3))) unsigned int*)lds, 16, 0, 0);
}

static __device__ __forceinline__ void bar() {
    asm volatile("s_barrier" ::: "memory");
}
static __device__ __forceinline__ void vm0() {
    asm volatile("s_waitcnt vmcnt(0)" ::: "memory");
}
static __device__ __forceinline__ void lgkm0() {
    asm volatile("s_waitcnt lgkmcnt(0)" ::: "memory");
}

// ws layout (bytes):
//   [0,       589824)  aggb3 [B][q(4)][tap(9)][ch(2)][co(64)][8ci] bf16
//   [589824,  589952)  zero pad (128 B)
#define WS_PAD_OFF 589824

// ---------------------------------------------------------------------------
// Kernel 1: aggregate weights -> bf16, layout aggb3[b][q][tap][ch][co][8ci]
// (q = ci/16, ch = (ci>>3)&1) + zero pad.  (proven round 8)
// ---------------------------------------------------------------------------
__global__ __launch_bounds__(256) void prep_weights_kernel(
    const float* __restrict__ att,     // [B][10]
    const float* __restrict__ weight,  // [COUT][CIN][9]
    const float* __restrict__ tb, const float* __restrict__ tq,
    const float* __restrict__ tn, const float* __restrict__ tx,
    const float* __restrict__ mb, const float* __restrict__ mq,
    const float* __restrict__ mn, const float* __restrict__ mx,
    unsigned short* __restrict__ aggb)
{
    int idx = blockIdx.x * 256 + threadIdx.x;
    if (idx < 64) aggb[294912 + idx] = 0;          // zero pad region (128 B)
    if (idx >= B_ * 9 * COUT_ * CIN_) return;
    int b    = idx / (9 * COUT_ * CIN_);
    int rem  = idx - b * (9 * COUT_ * CIN_);
    int tap  = rem / (COUT_ * CIN_);
    int rem2 = rem & (COUT_ * CIN_ - 1);
    int co   = rem2 >> 6;
    int ci   = rem2 & 63;

    int r  = (co * CIN_ + ci) * 9 + tap;   // [co][ci][kh][kw]
    int cc = co * CIN_ + ci;

    float a0 = att[b * 10 + 0];
    float a1 = att[b * 10 + 1];
    float a2 = att[b * 10 + 2];
    float val = weight[r]
              + tb[r] * mb[cc] * a1
              + tq[r] * mq[cc] * a2
              + (tn[r] * mn[cc] + tx[r] * mx[cc]) * a0;
    int q  = ci >> 4;
    int ch = (ci >> 3) & 1;
    int o  = ci & 7;
    aggb[((((b * 4 + q) * 9 + tap) * 2 + ch) * 64 + co) * 8 + o] = f2bf(val);
}

// ---------------------------------------------------------------------------
// Kernel 2 (FUSED, reg-staged): implicit-GEMM conv from fp32 NCHW directly.
// Block 512 = 8 waves; tile 64co x 8 rows x 64 px; 4 phases x 16 ci.
// Per phase: [x(p) regs + Wd(p) DMA arrived] -> convert regs->Xb (cvt_pk +
// ds_write, ~8-way max) -> issue Wd(p+1) DMA + x(p+1) reg loads (fly across
// compute) -> bar -> compute (36 MFMA, B-reads <=2-way conflict) -> bar.
// Xb single-buffer (convert/compute bar-separated); Wd double (DMA in
// flight). LDS 59264 B -> 2 blocks/CU; launch_bounds caps VGPR<=128.
// Xb layout: slot-pair sp = row*35 + (c'>>1), c' = px-(x0-4); 64B/pair:
//   byte = sp*64 + 32*(p̃^(sp&1)^((sp>>1)&1)) + 16*(hc^((sp>>2)&1)) + 4*q
// (p̃ = c'&1, hc = ci-half, q = ci-quad) — all 8 16B residues per 8 read
// lanes (<=2-way), write lanes spread ~8 banks.
// ---------------------------------------------------------------------------
__global__ __launch_bounds__(512, 4) void conv_kernel(
    const float* __restrict__ x,            // [B][CIN][H][W] fp32
    const unsigned char* __restrict__ wsb,  // d_ws base (aggb3 + zpad)
    const float* __restrict__ bias,         // [COUT]
    float* __restrict__ out)                // [B][COUT][H][W] fp32
{
    __shared__ __align__(16) unsigned char Xb[22400];      // 350 slot-pairs
    __shared__ __align__(16) unsigned char Wd[2][18432];

    const int t = threadIdx.x;

    int bid = blockIdx.x;
    int bz  = bid & 7;            // batch = XCD
    int idx = bid >> 3;
    int ct  = idx >> 5;           // col tile 0..3
    int rt  = idx & 31;           // row tile 0..31 (row-adjacent on same XCD)
    const int x0 = ct * 64;
    const int y0 = rt * 8;

    const int l  = t & 63;
    const int w  = t >> 6;        // wave -> output row
    const int lp = l & 31;
    const int lk = l >> 5;

    const float* xB = x + ((size_t)bz << 22);          // bz*CIN*HW floats
    const unsigned char* wbB  = wsb + (size_t)bz * 73728;
    const float* zpad = (const float*)(wsb + WS_PAD_OFF);

    // ---- staging job precompute: j = (cp*10+row)*18 + k, 1440 jobs ----
    int  joff[3], jsp[3], jcp[3], jk[3];
    bool jval[3], jlive[3];
#pragma unroll
    for (int i = 0; i < 3; ++i) {
        int j   = i * 512 + t;
        jlive[i] = (j < 1440);
        int cp  = j / 180;
        int r   = j - cp * 180;
        int row = r / 18;
        int k   = r - row * 18;
        int gy  = y0 + row - 1;
        int gx0 = x0 - 4 + 4 * k;
        jval[i] = jlive[i] && ((unsigned)gy < H_) && (gx0 >= 0) && (gx0 + 3 < W_);
        joff[i] = ((2 * cp) << 16) + gy * W_ + gx0;    // float offset (ci=2cp plane)
        jsp[i]  = row * 35 + 2 * k;
        jcp[i]  = cp;
        jk[i]   = k;
    }

    float4 av[3], bv[3];

    auto issue_x = [&](int p) {                        // loads x(p) -> regs
        const int pofs = p * 16 * HW_;                 // +16 ci planes
#pragma unroll
        for (int i = 0; i < 3; ++i) {
            const float* sa = jval[i] ? (xB + joff[i] + pofs)       : zpad;
            const float* sb = jval[i] ? (xB + joff[i] + pofs + HW_) : zpad;
            av[i] = *(const float4*)sa;
            bv[i] = *(const float4*)sb;
        }
    };
    auto issue_w = [&](int p) {                        // Wd[p&1] <- 18432 B, linear
        const unsigned char* src = wbB + p * 18432;
        char* dst = (char*)Wd[p & 1];
        gload16(dst + t * 16,        src + t * 16);
        gload16(dst + 8192 + t * 16, src + 8192 + t * 16);
        if (t < 128)
            gload16(dst + 16384 + t * 16, src + 16384 + t * 16);
    };
    auto convert = [&]() {                             // regs -> Xb
#pragma unroll
        for (int i = 0; i < 3; ++i) {
            if (!jlive[i]) continue;
            const int cp = jcp[i];
            const int cq = cp & 3, chn = cp >> 2;
#pragma unroll
            for (int m = 0; m < 2; ++m) {
                if (jk[i] == 17 && m == 1) continue;   // c' 70/71: dead + OOB
                int sp = jsp[i] + m;
                int base = sp * 64 + (16 * (chn ^ ((sp >> 2) & 1))) + 4 * cq;
                int xl = ((sp & 1) ^ ((sp >> 1) & 1)) << 5;
                float pa0 = (m == 0) ? av[i].x : av[i].z;
                float pb0 = (m == 0) ? bv[i].x : bv[i].z;
                float pa1 = (m == 0) ? av[i].y : av[i].w;
                float pb1 = (m == 0) ? bv[i].y : bv[i].w;
                *(unsigned*)(Xb + (base + (0 ^ xl)))  = cvtpk(pa0, pb0);
                *(unsigned*)(Xb + (base + (32 ^ xl))) = cvtpk(pa1, pb1);
            }
        }
    };

    f32x16 acc[2][2];
#pragma unroll
    for (int i = 0; i < 16; ++i) {
        acc[0][0][i] = 0.f; acc[0][1][i] = 0.f;
        acc[1][0][i] = 0.f; acc[1][1][i] = 0.f;
    }

    const int c0 = 3 + lp;        // c' base for this lane

    auto compute = [&](const unsigned char* wdq) {
        const char* Ab = (const char*)wdq + lk * 1024 + lp * 16;
        __builtin_amdgcn_s_setprio(1);
#pragma unroll
        for (int tap = 0; tap < 9; ++tap) {
            const int kh = tap / 3;
            const int kw = tap - kh * 3;
            short8 a0 = *(const short8*)(Ab + tap * 2048);
            short8 a1 = *(const short8*)(Ab + tap * 2048 + 512);
#pragma unroll
            for (int pb = 0; pb < 2; ++pb) {
                int cc = c0 + kw + pb * 32;
                int sp = (w + kh) * 35 + (cc >> 1);
                int byteo = sp * 64
                          + 32 * ((cc & 1) ^ (sp & 1) ^ ((sp >> 1) & 1))
                          + 16 * (lk ^ ((sp >> 2) & 1));
                short8 bvv = *(const short8*)(Xb + byteo);
                acc[0][pb] = __builtin_amdgcn_mfma_f32_32x32x16_bf16(a0, bvv, acc[0][pb], 0, 0, 0);
                acc[1][pb] = __builtin_amdgcn_mfma_f32_32x32x16_bf16(a1, bvv, acc[1][pb], 0, 0, 0);
            }
        }
        __builtin_amdgcn_s_setprio(0);
    };

    // ---- pipeline ----
    issue_w(0);
    issue_x(0);
#pragma unroll
    for (int p = 0; p < 4; ++p) {
        vm0();                    // x(p) regs + Wd[p&1] DMA arrived (this wave)
        convert();                // -> Xb
        if (p < 3) { issue_w(p + 1); issue_x(p + 1); }  // fly across compute
        lgkm0();
        bar();                    // Xb + Wd visible to all waves
        compute(Wd[p & 1]);
        bar();                    // all waves done with Xb/Wd before overwrite
    }

    // ---- epilogue: bias + store (full 128B line segments) ----
    const size_t ob = (size_t)bz * COUT_ * HW_ + (size_t)(y0 + w) * W_ + x0;
#pragma unroll
    for (int cg = 0; cg < 2; ++cg) {
#pragma unroll
        for (int g = 0; g < 16; ++g) {
            int co = cg * 32 + (g & 3) + 8 * (g >> 2) + 4 * lk;
            float bs = bias[co];
            out[ob + (size_t)co * HW_ + lp]      = acc[cg][0][g] + bs;
            out[ob + (size_t)co * HW_ + 32 + lp] = acc[cg][1][g] + bs;
        }
    }
}

extern "C" void kernel_launch(void* const* d_in, const int* in_sizes, int n_in,
                              void* d_out, int out_size, void* d_ws, size_t ws_size,
                              hipStream_t stream) {
    const float* x      = (const float*)d_in[0];
    const float* att    = (const float*)d_in[1];
    const float* weight = (const float*)d_in[2];
    const float* tb     = (const float*)d_in[3];
    const float* tq     = (const float*)d_in[4];
    const float* tn     = (const float*)d_in[5];
    const float* tx     = (const float*)d_in[6];
    const float* mb     = (const float*)d_in[7];
    const float* mq     = (const float*)d_in[8];
    const float* mn     = (const float*)d_in[9];
    const float* mx     = (const float*)d_in[10];
    const float* bias   = (const float*)d_in[11];

    unsigned short* aggb = (unsigned short*)d_ws;   // 590 KB incl. pad
    float* outp = (float*)d_out;

    int n_agg = B_ * 9 * COUT_ * CIN_;
    prep_weights_kernel<<<(n_agg + 255) / 256, 256, 0, stream>>>(
        att, weight, tb, tq, tn, tx, mb, mq, mn, mx, aggb);

    conv_kernel<<<1024, 512, 0, stream>>>(
        x, (const unsigned char*)d_ws, bias, outp);
}